// Round 1
// baseline (412.963 us; speedup 1.0000x reference)
//
#include <hip/hip_runtime.h>
#include <hip/hip_bf16.h>
#include <cmath>

typedef unsigned short u16;
typedef unsigned int u32;

__device__ __forceinline__ float bf2f(u16 b) {
    return __uint_as_float(((u32)b) << 16);
}
__device__ __forceinline__ u16 f2bf(float f) {
    u32 u = __float_as_uint(f);
    u = (u + 0x7fffu + ((u >> 16) & 1u)) >> 16;  // RNE; inputs never NaN
    return (u16)u;
}

__device__ __forceinline__ float warp_sum(float v) {
#pragma unroll
    for (int o = 32; o > 0; o >>= 1) v += __shfl_down(v, o, 64);
    return v;
}
__device__ __forceinline__ float warp_max(float v) {
#pragma unroll
    for (int o = 32; o > 0; o >>= 1) v = fmaxf(v, __shfl_down(v, o, 64));
    return v;
}
// blockDim.x == 256 (4 waves) assumed
__device__ float block_sum(float v) {
    __shared__ float s[4];
    v = warp_sum(v);
    __syncthreads();
    if ((threadIdx.x & 63) == 0) s[threadIdx.x >> 6] = v;
    __syncthreads();
    return s[0] + s[1] + s[2] + s[3];
}
__device__ float block_max(float v) {
    __shared__ float s[4];
    v = warp_max(v);
    __syncthreads();
    if ((threadIdx.x & 63) == 0) s[threadIdx.x >> 6] = v;
    __syncthreads();
    return fmaxf(fmaxf(s[0], s[1]), fmaxf(s[2], s[3]));
}

// One workgroup (256 threads) per row. Fused: row softmax of attention_logits,
// x = sigmoid(logits/0.5)*attn*valid, bf16 x written to ws, per-row reductions.
__global__ __launch_bounds__(256) void k_main(
    const float* __restrict__ dist, const float* __restrict__ logit,
    const float* __restrict__ attn, const int* __restrict__ srcp,
    u16* __restrict__ xb, float* __restrict__ out_flow,
    float* __restrict__ cnt_row, float* __restrict__ s2_row,
    float* __restrict__ pc_row, float* __restrict__ v, int n) {
    const int row = blockIdx.x;
    const int t = threadIdx.x;
    const int K = n >> 10;  // float4 groups per thread (n=4096 -> 4)
    const size_t base = (size_t)row * n;

    // phase 1: softmax stats; keep the row's attention logits in registers
    float a[16];
    float mx = -3.0e38f;
    for (int k = 0; k < K; ++k) {
        float4 f = *(const float4*)(attn + base + 4 * t + 1024 * k);
        a[4 * k + 0] = f.x; a[4 * k + 1] = f.y;
        a[4 * k + 2] = f.z; a[4 * k + 3] = f.w;
        mx = fmaxf(mx, fmaxf(fmaxf(f.x, f.y), fmaxf(f.z, f.w)));
    }
    float m = block_max(mx);
    float se = 0.f;
    for (int i = 0; i < 4 * K; ++i) { a[i] = __expf(a[i] - m); se += a[i]; }
    float Z = block_sum(se);
    float invZ = 1.0f / Z;
    const int src = *srcp;

    // phase 2: compute x, store bf16, accumulate reductions
    float cnt = 0.f, s1 = 0.f, s2 = 0.f, pc = 0.f;
    for (int k = 0; k < K; ++k) {
        const int col = 4 * t + 1024 * k;
        float4 df = *(const float4*)(dist + base + col);
        float4 lf = *(const float4*)(logit + base + col);
        float dv[4] = {df.x, df.y, df.z, df.w};
        float lv[4] = {lf.x, lf.y, lf.z, lf.w};
        float xv[4];
        ushort4 pk;
        u16* pkp = (u16*)&pk;
#pragma unroll
        for (int q = 0; q < 4; ++q) {
            float valid = (dv[q] < 1.0e6f) ? 1.f : 0.f;
            float sg = 1.0f / (1.0f + __expf(-2.0f * lv[q]));  // sigmoid(l/0.5)
            float x = sg * (a[4 * k + q] * invZ) * valid;
            xv[q] = x;
            cnt += valid;
            s1 += x;
            s2 += x * x;
            pc += dv[q] * x;  // x==0 exactly on invalid arcs -> contributes 0
            pkp[q] = f2bf(x);
        }
        *(ushort4*)(xb + base + col) = pk;
        if (row == src) {
            float4 vf; vf.x = xv[0]; vf.y = xv[1]; vf.z = xv[2]; vf.w = xv[3];
            *(float4*)(v + col) = vf;
        }
    }
    float s1t = block_sum(s1);
    float cntt = block_sum(cnt);
    float s2t = block_sum(s2);
    float pct = block_sum(pc);
    if (t == 0) {
        out_flow[row] = s1t;   // row sum of x
        cnt_row[row] = cntt;
        s2_row[row] = s2t;
        pc_row[row] = pct;
    }
}

// column-sum partials: ip[by][j] = sum over a 128-row chunk of x[:,j]
__global__ __launch_bounds__(256) void k_colsum(
    const u16* __restrict__ xb, float* __restrict__ ip, int n, int rows_per) {
    const int j = blockIdx.x * 256 + threadIdx.x;
    const int i0 = blockIdx.y * rows_per;
    float acc = 0.f;
    for (int i = 0; i < rows_per; ++i) acc += bf2f(xb[(size_t)(i0 + i) * n + j]);
    ip[(size_t)blockIdx.y * n + j] = acc;
}

// up[by][j] = sum_i v[i0+i] * x[i0+i][j]  (vector-matrix partial)
__global__ __launch_bounds__(256) void k_vecmat(
    const u16* __restrict__ xb, const float* __restrict__ v,
    float* __restrict__ up, int n, int rows_per) {
    __shared__ float vl[128];
    const int j = blockIdx.x * 256 + threadIdx.x;
    const int i0 = blockIdx.y * rows_per;
    if (threadIdx.x < rows_per) vl[threadIdx.x] = v[i0 + threadIdx.x];
    __syncthreads();
    float acc = 0.f;
    for (int i = 0; i < rows_per; ++i)
        acc += vl[i] * bf2f(xb[(size_t)(i0 + i) * n + j]);
    up[(size_t)blockIdx.y * n + j] = acc;
}

// v[j] += sum over chunks of up[c][j]
__global__ __launch_bounds__(256) void k_update(
    float* __restrict__ v, const float* __restrict__ up, int n, int nchunk) {
    const int j = blockIdx.x * 256 + threadIdx.x;
    float acc = 0.f;
    for (int c = 0; c < nchunk; ++c) acc += up[(size_t)c * n + j];
    v[j] += acc;
}

__global__ __launch_bounds__(256) void k_final(
    const float* __restrict__ out_flow, const float* __restrict__ ip,
    const float* __restrict__ cnt_row, const float* __restrict__ s2_row,
    const float* __restrict__ pc_row, const float* __restrict__ v,
    const int* __restrict__ srcp, const int* __restrict__ dstp,
    float* __restrict__ out, int n, int nchunk) {
    const int t = threadIdx.x;
    const int src = *srcp, dst = *dstp;
    float facc = 0.f, s1 = 0.f, cnt = 0.f, s2 = 0.f, pc = 0.f;
    for (int j = t; j < n; j += 256) {
        float infl = 0.f;
        for (int c = 0; c < nchunk; ++c) infl += ip[(size_t)c * n + j];
        float d = out_flow[j] - infl;
        if (j == src) d -= 1.f;
        if (j == dst) d += 1.f;
        facc += d * d;
        s1 += out_flow[j];
        cnt += cnt_row[j];
        s2 += s2_row[j];
        pc += pc_row[j];
    }
    float flow = block_sum(facc);
    float S1 = block_sum(s1);
    float NE = block_sum(cnt);
    float S2 = block_sum(s2);
    float PC = block_sum(pc);
    if (t == 0) {
        float nf = (float)n;
        float nn = nf * nf;
        float density = NE / nn;
        float mu2 = 10.f * (1.f + density);  // mu3 == mu2
        float r = v[dst];                    // reach[source,destination]
        float om = 1.f - r;
        float res = PC / (NE + 1e-6f)        // mu1 * path_cost / n_edges
                  + mu2 * flow / nf
                  + mu2 * (S1 - S2) / nn     // binary penalty
                  + 20.f * om * om
                  + 5.f * S1 / nn;           // sparsity
        out[0] = res;
    }
}

extern "C" void kernel_launch(void* const* d_in, const int* in_sizes, int n_in,
                              void* d_out, int out_size, void* d_ws, size_t ws_size,
                              hipStream_t stream) {
    const float* dist = (const float*)d_in[0];
    const float* logit = (const float*)d_in[1];
    const float* attn = (const float*)d_in[2];
    const int* srcp = (const int*)d_in[3];
    const int* dstp = (const int*)d_in[4];
    const int n = (int)(std::sqrt((double)in_sizes[0]) + 0.5);  // 4096
    const size_t nn = (size_t)n * n;

    char* ws = (char*)d_ws;
    u16* xb = (u16*)ws;                       // bf16 x, 2*nn bytes
    float* f = (float*)(ws + nn * sizeof(u16));
    float* out_flow = f; f += n;
    float* cnt_row = f;  f += n;
    float* s2_row = f;   f += n;
    float* pc_row = f;   f += n;
    float* v = f;        f += n;
    float* up = f;       f += (size_t)32 * n;
    float* ip = f;       f += (size_t)32 * n;

    const int RC = 32;
    const int rows_per = n / RC;  // 128

    k_main<<<n, 256, 0, stream>>>(dist, logit, attn, srcp, xb, out_flow,
                                  cnt_row, s2_row, pc_row, v, n);
    k_colsum<<<dim3(n / 256, RC), 256, 0, stream>>>(xb, ip, n, rows_per);
    for (int it = 0; it < 10; ++it) {
        k_vecmat<<<dim3(n / 256, RC), 256, 0, stream>>>(xb, v, up, n, rows_per);
        k_update<<<n / 256, 256, 0, stream>>>(v, up, n, RC);
    }
    k_final<<<1, 256, 0, stream>>>(out_flow, ip, cnt_row, s2_row, pc_row, v,
                                   srcp, dstp, (float*)d_out, n, RC);
}

// Round 2
// 143.643 us; speedup vs baseline: 2.8749x; 2.8749x over previous
//
#include <hip/hip_runtime.h>
#include <hip/hip_bf16.h>
#include <cmath>

typedef unsigned short u16;
typedef unsigned int u32;

__device__ __forceinline__ float bf2f(u16 b) {
    return __uint_as_float(((u32)b) << 16);
}
__device__ __forceinline__ u16 f2bf(float f) {
    u32 u = __float_as_uint(f);
    u = (u + 0x7fffu + ((u >> 16) & 1u)) >> 16;  // RNE; inputs never NaN
    return (u16)u;
}

__device__ __forceinline__ float warp_sum(float v) {
#pragma unroll
    for (int o = 32; o > 0; o >>= 1) v += __shfl_down(v, o, 64);
    return v;
}
__device__ __forceinline__ float warp_max(float v) {
#pragma unroll
    for (int o = 32; o > 0; o >>= 1) v = fmaxf(v, __shfl_down(v, o, 64));
    return v;
}
// blockDim.x == 256 (4 waves) assumed
__device__ float block_sum(float v) {
    __shared__ float s[4];
    v = warp_sum(v);
    __syncthreads();
    if ((threadIdx.x & 63) == 0) s[threadIdx.x >> 6] = v;
    __syncthreads();
    return s[0] + s[1] + s[2] + s[3];
}
__device__ float block_max(float v) {
    __shared__ float s[4];
    v = warp_max(v);
    __syncthreads();
    if ((threadIdx.x & 63) == 0) s[threadIdx.x >> 6] = v;
    __syncthreads();
    return fmaxf(fmaxf(s[0], s[1]), fmaxf(s[2], s[3]));
}

// One workgroup (256 threads) per row. Fused: row softmax of attention_logits,
// x = sigmoid(logits/0.5)*attn*valid, bf16 x written to ws, per-row reductions.
__global__ __launch_bounds__(256) void k_main(
    const float* __restrict__ dist, const float* __restrict__ logit,
    const float* __restrict__ attn, const int* __restrict__ srcp,
    u16* __restrict__ xb, float* __restrict__ out_flow,
    float* __restrict__ cnt_row, float* __restrict__ s2_row,
    float* __restrict__ pc_row, float* __restrict__ v, int n) {
    const int row = blockIdx.x;
    const int t = threadIdx.x;
    const int K = n >> 10;  // float4 groups per thread (n=4096 -> 4)
    const size_t base = (size_t)row * n;

    // phase 1: softmax stats; keep the row's attention logits in registers
    float a[16];
    float mx = -3.0e38f;
    for (int k = 0; k < K; ++k) {
        float4 f = *(const float4*)(attn + base + 4 * t + 1024 * k);
        a[4 * k + 0] = f.x; a[4 * k + 1] = f.y;
        a[4 * k + 2] = f.z; a[4 * k + 3] = f.w;
        mx = fmaxf(mx, fmaxf(fmaxf(f.x, f.y), fmaxf(f.z, f.w)));
    }
    float m = block_max(mx);
    float se = 0.f;
    for (int i = 0; i < 4 * K; ++i) { a[i] = __expf(a[i] - m); se += a[i]; }
    float Z = block_sum(se);
    float invZ = 1.0f / Z;
    const int src = *srcp;

    // phase 2: compute x, store bf16, accumulate reductions
    float cnt = 0.f, s1 = 0.f, s2 = 0.f, pc = 0.f;
    for (int k = 0; k < K; ++k) {
        const int col = 4 * t + 1024 * k;
        float4 df = *(const float4*)(dist + base + col);
        float4 lf = *(const float4*)(logit + base + col);
        float dv[4] = {df.x, df.y, df.z, df.w};
        float lv[4] = {lf.x, lf.y, lf.z, lf.w};
        float xv[4];
        ushort4 pk;
        u16* pkp = (u16*)&pk;
#pragma unroll
        for (int q = 0; q < 4; ++q) {
            float valid = (dv[q] < 1.0e6f) ? 1.f : 0.f;
            float sg = 1.0f / (1.0f + __expf(-2.0f * lv[q]));  // sigmoid(l/0.5)
            float x = sg * (a[4 * k + q] * invZ) * valid;
            xv[q] = x;
            cnt += valid;
            s1 += x;
            s2 += x * x;
            pc += dv[q] * x;  // x==0 exactly on invalid arcs -> contributes 0
            pkp[q] = f2bf(x);
        }
        *(ushort4*)(xb + base + col) = pk;
        if (row == src) {
            float4 vf; vf.x = xv[0]; vf.y = xv[1]; vf.z = xv[2]; vf.w = xv[3];
            *(float4*)(v + col) = vf;
        }
    }
    float s1t = block_sum(s1);
    float cntt = block_sum(cnt);
    float s2t = block_sum(s2);
    float pct = block_sum(pc);
    if (t == 0) {
        out_flow[row] = s1t;   // row sum of x
        cnt_row[row] = cntt;
        s2_row[row] = s2t;
        pc_row[row] = pct;
    }
}

// One iteration of v <- v + v@x, fused with the reduction of the PREVIOUS
// iteration's partials (each block redundantly reduces its 128-row slice:
// 16.5 KB of L2-hot data, cheaper than a separate kernel launch).
// bx==0 blocks persist the reduced v (state s_{t-1}) into v_out for later use.
// FIRST: also emit unweighted column-sum partials (in_flow) for free.
template <int FIRST>
__global__ __launch_bounds__(256) void k_iter(
    const u16* __restrict__ xb, const float* __restrict__ v_in,
    const float* __restrict__ up_in, float* __restrict__ v_out,
    float* __restrict__ up_out, float* __restrict__ ip, int n) {
    __shared__ float vl[128];
    const int t = threadIdx.x;
    const int j = blockIdx.x * 256 + t;
    const int i0 = blockIdx.y * 128;
    if (t < 128) {
        float a = v_in[i0 + t];
        if (!FIRST) {
#pragma unroll 8
            for (int c = 0; c < 32; ++c) a += up_in[(size_t)c * n + i0 + t];
        }
        vl[t] = a;
        if (blockIdx.x == 0) v_out[i0 + t] = a;
    }
    __syncthreads();
    float acc = 0.f, cs = 0.f;
#pragma unroll 8
    for (int i = 0; i < 128; ++i) {
        float xv = bf2f(xb[(size_t)(i0 + i) * n + j]);
        acc = fmaf(vl[i], xv, acc);
        if (FIRST) cs += xv;
    }
    up_out[(size_t)blockIdx.y * n + j] = acc;
    if (FIRST) ip[(size_t)blockIdx.y * n + j] = cs;
}

// Parallel final-phase stage 1: 16 blocks, each owns 256 columns.
// Computes in_flow[j] from the 32 column-sum partials, the flow-penalty
// term d_j^2 (with src/dst corrections), and partial sums of the row stats.
__global__ __launch_bounds__(256) void k_reduce(
    const float* __restrict__ out_flow, const float* __restrict__ ip,
    const float* __restrict__ cnt_row, const float* __restrict__ s2_row,
    const float* __restrict__ pc_row, const int* __restrict__ srcp,
    const int* __restrict__ dstp, float* __restrict__ pb, int n) {
    const int t = threadIdx.x;
    const int j = blockIdx.x * 256 + t;
    const int src = *srcp, dst = *dstp;
    float infl = 0.f;
#pragma unroll 8
    for (int c = 0; c < 32; ++c) infl += ip[(size_t)c * n + j];
    float d = out_flow[j] - infl;
    if (j == src) d -= 1.f;
    if (j == dst) d += 1.f;
    float f = block_sum(d * d);
    float s1 = block_sum(out_flow[j]);
    float cnt = block_sum(cnt_row[j]);
    float s2 = block_sum(s2_row[j]);
    float pc = block_sum(pc_row[j]);
    if (t == 0) {
        float* p = pb + blockIdx.x * 5;
        p[0] = f; p[1] = s1; p[2] = cnt; p[3] = s2; p[4] = pc;
    }
}

// Final tiny kernel: reduce 16 partial quintuples + compute r and the loss.
__global__ __launch_bounds__(256) void k_final(
    const float* __restrict__ pb, const float* __restrict__ v_last,
    const float* __restrict__ up_last, const int* __restrict__ dstp,
    float* __restrict__ out, int n, int nblk) {
    const int t = threadIdx.x;
    const int dst = *dstp;
    float flow = block_sum(t < nblk ? pb[t * 5 + 0] : 0.f);
    float S1   = block_sum(t < nblk ? pb[t * 5 + 1] : 0.f);
    float NE   = block_sum(t < nblk ? pb[t * 5 + 2] : 0.f);
    float S2   = block_sum(t < nblk ? pb[t * 5 + 3] : 0.f);
    float PC   = block_sum(t < nblk ? pb[t * 5 + 4] : 0.f);
    float r = block_sum(t < 32 ? up_last[(size_t)t * n + dst] : 0.f);
    if (t == 0) {
        r += v_last[dst];  // reach[source, destination]
        float nf = (float)n;
        float nn = nf * nf;
        float density = NE / nn;
        float mu2 = 10.f * (1.f + density);  // mu3 == mu2
        float om = 1.f - r;
        float res = PC / (NE + 1e-6f)        // mu1 * path_cost / n_edges
                  + mu2 * flow / nf
                  + mu2 * (S1 - S2) / nn     // binary penalty
                  + 20.f * om * om
                  + 5.f * S1 / nn;           // sparsity
        out[0] = res;
    }
}

extern "C" void kernel_launch(void* const* d_in, const int* in_sizes, int n_in,
                              void* d_out, int out_size, void* d_ws, size_t ws_size,
                              hipStream_t stream) {
    const float* dist = (const float*)d_in[0];
    const float* logit = (const float*)d_in[1];
    const float* attn = (const float*)d_in[2];
    const int* srcp = (const int*)d_in[3];
    const int* dstp = (const int*)d_in[4];
    const int n = (int)(std::sqrt((double)in_sizes[0]) + 0.5);  // 4096
    const size_t nn = (size_t)n * n;

    char* ws = (char*)d_ws;
    u16* xb = (u16*)ws;                       // bf16 x, 2*nn bytes
    float* f = (float*)(ws + nn * sizeof(u16));
    float* out_flow = f; f += n;
    float* cnt_row = f;  f += n;
    float* s2_row = f;   f += n;
    float* pc_row = f;   f += n;
    float* vA = f;       f += n;
    float* vB = f;       f += n;
    float* upA = f;      f += (size_t)32 * n;
    float* upB = f;      f += (size_t)32 * n;
    float* ip = f;       f += (size_t)32 * n;
    float* pb = f;       f += 128;

    const dim3 ig(n / 256, 32);  // (16, 32): 256 cols x 128 rows per block

    k_main<<<n, 256, 0, stream>>>(dist, logit, attn, srcp, xb, out_flow,
                                  cnt_row, s2_row, pc_row, vA, n);

    // iteration 1: vecmat + column sums (in_flow partials) in one pass
    k_iter<1><<<ig, 256, 0, stream>>>(xb, vA, nullptr, vB, upA, ip, n);
    float* vin = vB;  float* uin = upA;
    float* vout;      float* uout;
    for (int it = 2; it <= 10; ++it) {
        vout = (it & 1) ? vB : vA;
        uout = (it & 1) ? upA : upB;
        k_iter<0><<<ig, 256, 0, stream>>>(xb, vin, uin, vout, uout, nullptr, n);
        vin = vout; uin = uout;
    }
    // state: vin holds s_9, uin holds partials of the 10th update

    k_reduce<<<n / 256, 256, 0, stream>>>(out_flow, ip, cnt_row, s2_row,
                                          pc_row, srcp, dstp, pb, n);
    k_final<<<1, 256, 0, stream>>>(pb, vin, uin, dstp, (float*)d_out, n,
                                   n / 256);
}

// Round 3
// 134.446 us; speedup vs baseline: 3.0716x; 1.0684x over previous
//
#include <hip/hip_runtime.h>
#include <hip/hip_bf16.h>
#include <cmath>

typedef unsigned short u16;
typedef unsigned int u32;

__device__ __forceinline__ float bf2f(u16 b) {
    return __uint_as_float(((u32)b) << 16);
}
__device__ __forceinline__ u16 f2bf(float f) {
    u32 u = __float_as_uint(f);
    u = (u + 0x7fffu + ((u >> 16) & 1u)) >> 16;  // RNE; inputs never NaN
    return (u16)u;
}

__device__ __forceinline__ float warp_sum(float v) {
#pragma unroll
    for (int o = 32; o > 0; o >>= 1) v += __shfl_down(v, o, 64);
    return v;
}
__device__ __forceinline__ float warp_max(float v) {
#pragma unroll
    for (int o = 32; o > 0; o >>= 1) v = fmaxf(v, __shfl_down(v, o, 64));
    return v;
}
// blockDim.x == 256 (4 waves) assumed
__device__ float block_sum(float v) {
    __shared__ float s[4];
    v = warp_sum(v);
    __syncthreads();
    if ((threadIdx.x & 63) == 0) s[threadIdx.x >> 6] = v;
    __syncthreads();
    return s[0] + s[1] + s[2] + s[3];
}
__device__ float block_max(float v) {
    __shared__ float s[4];
    v = warp_max(v);
    __syncthreads();
    if ((threadIdx.x & 63) == 0) s[threadIdx.x >> 6] = v;
    __syncthreads();
    return fmaxf(fmaxf(s[0], s[1]), fmaxf(s[2], s[3]));
}

// One workgroup (256 threads) per row. Fused: row softmax of attention_logits,
// x = sigmoid(logits/0.5)*attn*valid, bf16 x written to ws, per-row reductions.
// K is COMPILE-TIME (float4 groups per thread) so all arrays stay in VGPRs
// (rule #20: runtime-indexed arrays spill to scratch — that was the round-2
// latency bug: VGPR_Count=28 proved a[16] lived in scratch).
template <int K>
__global__ __launch_bounds__(256) void k_main(
    const float* __restrict__ dist, const float* __restrict__ logit,
    const float* __restrict__ attn, const int* __restrict__ srcp,
    u16* __restrict__ xb, float* __restrict__ out_flow,
    float* __restrict__ cnt_row, float* __restrict__ s2_row,
    float* __restrict__ pc_row, float* __restrict__ v, int n) {
    const int row = blockIdx.x;
    const int t = threadIdx.x;
    const size_t base = (size_t)row * n;

    // phase 1: issue all attention loads up front, then softmax stats
    float4 af[K];
#pragma unroll
    for (int k = 0; k < K; ++k)
        af[k] = *(const float4*)(attn + base + 4 * t + 1024 * k);
    float a[4 * K];
    float mx = -3.0e38f;
#pragma unroll
    for (int k = 0; k < K; ++k) {
        a[4 * k + 0] = af[k].x; a[4 * k + 1] = af[k].y;
        a[4 * k + 2] = af[k].z; a[4 * k + 3] = af[k].w;
        mx = fmaxf(mx, fmaxf(fmaxf(af[k].x, af[k].y), fmaxf(af[k].z, af[k].w)));
    }
    float m = block_max(mx);
    float se = 0.f;
#pragma unroll
    for (int i = 0; i < 4 * K; ++i) { a[i] = __expf(a[i] - m); se += a[i]; }
    float Z = block_sum(se);
    float invZ = 1.0f / Z;
    const int src = *srcp;

    // phase 2: issue ALL dist/logit loads first (2*K float4 in flight),
    // then compute x, store bf16, accumulate reductions.
    float4 d4[K], l4[K];
#pragma unroll
    for (int k = 0; k < K; ++k) {
        const int col = 4 * t + 1024 * k;
        d4[k] = *(const float4*)(dist + base + col);
        l4[k] = *(const float4*)(logit + base + col);
    }
    float cnt = 0.f, s1 = 0.f, s2 = 0.f, pc = 0.f;
#pragma unroll
    for (int k = 0; k < K; ++k) {
        const int col = 4 * t + 1024 * k;
        float dv[4] = {d4[k].x, d4[k].y, d4[k].z, d4[k].w};
        float lv[4] = {l4[k].x, l4[k].y, l4[k].z, l4[k].w};
        float xv[4];
        ushort4 pk;
        u16* pkp = (u16*)&pk;
#pragma unroll
        for (int q = 0; q < 4; ++q) {
            float valid = (dv[q] < 1.0e6f) ? 1.f : 0.f;
            float sg = 1.0f / (1.0f + __expf(-2.0f * lv[q]));  // sigmoid(l/0.5)
            float x = sg * (a[4 * k + q] * invZ) * valid;
            xv[q] = x;
            cnt += valid;
            s1 += x;
            s2 += x * x;
            pc += dv[q] * x;  // x==0 exactly on invalid arcs -> contributes 0
            pkp[q] = f2bf(x);
        }
        *(ushort4*)(xb + base + col) = pk;
        if (row == src) {
            float4 vf; vf.x = xv[0]; vf.y = xv[1]; vf.z = xv[2]; vf.w = xv[3];
            *(float4*)(v + col) = vf;
        }
    }
    float s1t = block_sum(s1);
    float cntt = block_sum(cnt);
    float s2t = block_sum(s2);
    float pct = block_sum(pc);
    if (t == 0) {
        out_flow[row] = s1t;   // row sum of x
        cnt_row[row] = cntt;
        s2_row[row] = s2t;
        pc_row[row] = pct;
    }
}

// One iteration of v <- v + v@x, fused with the reduction of the PREVIOUS
// iteration's partials. Each thread owns 4 consecutive columns (ushort4
// loads, 8 B/lane) over a rows_per-row chunk; unroll-8 keeps 8 independent
// loads in flight. Grid: (n/1024, 64) = 256 blocks at n=4096.
// bx==0 blocks persist the reduced v (state s_{t-1}) into v_out.
// FIRST: also emit unweighted column-sum partials (in_flow) for free.
template <int FIRST>
__global__ __launch_bounds__(256) void k_iter(
    const u16* __restrict__ xb, const float* __restrict__ v_in,
    const float* __restrict__ up_in, float* __restrict__ v_out,
    float* __restrict__ up_out, float* __restrict__ ip, int n, int rows_per) {
    __shared__ float vl[128];
    const int t = threadIdx.x;
    const int j0 = blockIdx.x * 1024 + t * 4;
    const int i0 = blockIdx.y * rows_per;
    const int nchunk = gridDim.y;
    if (t < rows_per) {
        float a = v_in[i0 + t];
        if (!FIRST) {
#pragma unroll 8
            for (int c = 0; c < nchunk; ++c) a += up_in[(size_t)c * n + i0 + t];
        }
        vl[t] = a;
        if (blockIdx.x == 0) v_out[i0 + t] = a;
    }
    __syncthreads();
    float4 acc = {0.f, 0.f, 0.f, 0.f};
    float4 cs = {0.f, 0.f, 0.f, 0.f};
#pragma unroll 8
    for (int i = 0; i < rows_per; ++i) {
        ushort4 xv = *(const ushort4*)(xb + (size_t)(i0 + i) * n + j0);
        float vi = vl[i];
        acc.x = fmaf(vi, bf2f(xv.x), acc.x);
        acc.y = fmaf(vi, bf2f(xv.y), acc.y);
        acc.z = fmaf(vi, bf2f(xv.z), acc.z);
        acc.w = fmaf(vi, bf2f(xv.w), acc.w);
        if (FIRST) {
            cs.x += bf2f(xv.x); cs.y += bf2f(xv.y);
            cs.z += bf2f(xv.z); cs.w += bf2f(xv.w);
        }
    }
    *(float4*)(up_out + (size_t)blockIdx.y * n + j0) = acc;
    if (FIRST) *(float4*)(ip + (size_t)blockIdx.y * n + j0) = cs;
}

// Parallel final-phase stage 1: 16 blocks, each owns 256 columns.
__global__ __launch_bounds__(256) void k_reduce(
    const float* __restrict__ out_flow, const float* __restrict__ ip,
    const float* __restrict__ cnt_row, const float* __restrict__ s2_row,
    const float* __restrict__ pc_row, const int* __restrict__ srcp,
    const int* __restrict__ dstp, float* __restrict__ pb, int n, int nchunk) {
    const int t = threadIdx.x;
    const int j = blockIdx.x * 256 + t;
    const int src = *srcp, dst = *dstp;
    float infl = 0.f;
#pragma unroll 8
    for (int c = 0; c < nchunk; ++c) infl += ip[(size_t)c * n + j];
    float d = out_flow[j] - infl;
    if (j == src) d -= 1.f;
    if (j == dst) d += 1.f;
    float f = block_sum(d * d);
    float s1 = block_sum(out_flow[j]);
    float cnt = block_sum(cnt_row[j]);
    float s2 = block_sum(s2_row[j]);
    float pc = block_sum(pc_row[j]);
    if (t == 0) {
        float* p = pb + blockIdx.x * 5;
        p[0] = f; p[1] = s1; p[2] = cnt; p[3] = s2; p[4] = pc;
    }
}

// Final tiny kernel: reduce 16 partial quintuples + compute r and the loss.
__global__ __launch_bounds__(256) void k_final(
    const float* __restrict__ pb, const float* __restrict__ v_last,
    const float* __restrict__ up_last, const int* __restrict__ dstp,
    float* __restrict__ out, int n, int nblk, int nchunk) {
    const int t = threadIdx.x;
    const int dst = *dstp;
    float flow = block_sum(t < nblk ? pb[t * 5 + 0] : 0.f);
    float S1   = block_sum(t < nblk ? pb[t * 5 + 1] : 0.f);
    float NE   = block_sum(t < nblk ? pb[t * 5 + 2] : 0.f);
    float S2   = block_sum(t < nblk ? pb[t * 5 + 3] : 0.f);
    float PC   = block_sum(t < nblk ? pb[t * 5 + 4] : 0.f);
    float r = block_sum(t < nchunk ? up_last[(size_t)t * n + dst] : 0.f);
    if (t == 0) {
        r += v_last[dst];  // reach[source, destination]
        float nf = (float)n;
        float nn = nf * nf;
        float density = NE / nn;
        float mu2 = 10.f * (1.f + density);  // mu3 == mu2
        float om = 1.f - r;
        float res = PC / (NE + 1e-6f)        // mu1 * path_cost / n_edges
                  + mu2 * flow / nf
                  + mu2 * (S1 - S2) / nn     // binary penalty
                  + 20.f * om * om
                  + 5.f * S1 / nn;           // sparsity
        out[0] = res;
    }
}

extern "C" void kernel_launch(void* const* d_in, const int* in_sizes, int n_in,
                              void* d_out, int out_size, void* d_ws, size_t ws_size,
                              hipStream_t stream) {
    const float* dist = (const float*)d_in[0];
    const float* logit = (const float*)d_in[1];
    const float* attn = (const float*)d_in[2];
    const int* srcp = (const int*)d_in[3];
    const int* dstp = (const int*)d_in[4];
    const int n = (int)(std::sqrt((double)in_sizes[0]) + 0.5);  // 4096
    const size_t nn = (size_t)n * n;

    const int RC = 64;              // row chunks (also in-flow partial count)
    const int rows_per = n / RC;    // 64 at n=4096

    char* ws = (char*)d_ws;
    u16* xb = (u16*)ws;                       // bf16 x, 2*nn bytes
    float* f = (float*)(ws + nn * sizeof(u16));
    float* out_flow = f; f += n;
    float* cnt_row = f;  f += n;
    float* s2_row = f;   f += n;
    float* pc_row = f;   f += n;
    float* vA = f;       f += n;
    float* vB = f;       f += n;
    float* upA = f;      f += (size_t)RC * n;
    float* upB = f;      f += (size_t)RC * n;
    float* ip = f;       f += (size_t)RC * n;
    float* pb = f;       f += 128;

    // K (float4 groups per thread) must be compile-time: dispatch on n.
    switch (n >> 10) {
        case 4: k_main<4><<<n, 256, 0, stream>>>(dist, logit, attn, srcp, xb,
                    out_flow, cnt_row, s2_row, pc_row, vA, n); break;
        case 2: k_main<2><<<n, 256, 0, stream>>>(dist, logit, attn, srcp, xb,
                    out_flow, cnt_row, s2_row, pc_row, vA, n); break;
        case 8: k_main<8><<<n, 256, 0, stream>>>(dist, logit, attn, srcp, xb,
                    out_flow, cnt_row, s2_row, pc_row, vA, n); break;
        default: k_main<1><<<n, 256, 0, stream>>>(dist, logit, attn, srcp, xb,
                    out_flow, cnt_row, s2_row, pc_row, vA, n); break;
    }

    const dim3 ig(n / 1024, RC);  // (4, 64) = 256 blocks at n=4096

    // iteration 1: vecmat + column sums (in_flow partials) in one pass
    k_iter<1><<<ig, 256, 0, stream>>>(xb, vA, nullptr, vB, upA, ip, n, rows_per);
    float* vin = vB;  float* uin = upA;
    float* vout;      float* uout;
    for (int it = 2; it <= 10; ++it) {
        vout = (it & 1) ? vB : vA;
        uout = (it & 1) ? upA : upB;
        k_iter<0><<<ig, 256, 0, stream>>>(xb, vin, uin, vout, uout, nullptr, n,
                                          rows_per);
        vin = vout; uin = uout;
    }
    // state: vin holds s_9, uin holds partials of the 10th update

    k_reduce<<<n / 256, 256, 0, stream>>>(out_flow, ip, cnt_row, s2_row,
                                          pc_row, srcp, dstp, pb, n, RC);
    k_final<<<1, 256, 0, stream>>>(pb, vin, uin, dstp, (float*)d_out, n,
                                   n / 256, RC);
}